// Round 1
// baseline (1519.502 us; speedup 1.0000x reference)
//
#include <hip/hip_runtime.h>
#include <hip/hip_fp16.h>
#include <hip/hip_cooperative_groups.h>
#include <math.h>

#define NN    4096
#define NITER 20
#define TPB   1024
#define NBLK  256     // == CU count; 1 block/CU (forced by LDS)
#define ROWS  16      // rows of E per block

// ---- dynamic LDS layout (total 149632 B <= 160 KiB/CU) ----
#define EH_OFF    0        // __half Eh[16][4096]           = 131072 B
#define VB_OFF    131072   // float  vbuf[4096]             =  16384 B
#define WRED_OFF  147456   // double wred[16][16]           =   2048 B
#define U_OFF     149504   // double u_lds[16]              =    128 B
#define SMEM_BYTES 149632
// final phase aliases lv[4096] (double, 32 KB) onto Eh space.

// exp of a double argument with fp32 exp + first-order fp64 correction.
__device__ __forceinline__ double exp_hi(double x) {
    float xf = (float)x;
    double dl = x - (double)xf;
    double e = (double)expf(xf);
    return fma(e, dl, e);
}

union U8  { ushort4 s; __half2 h[2]; };   // 8 B  = 4 halves
union U16 { uint4   u; __half2 h[4]; };   // 16 B = 8 halves

// One persistent cooperative kernel: E (fp16) lives in LDS for all 20
// Sinkhorn iterations. Per iteration:
//   C: partial col sums (block's 16 rows) -> part[b][j]      (fp32; fp64 @ t=19)
//   grid.sync
//   D: reduce 256 partials for block's 16 cols -> colacc[j]  (fp64)
//   grid.sync
//   R: v = 1/colacc staged in LDS; per-wave row sums -> u (block-local LDS)
// Last C-pass (t=19) recomputes E from W in fp64 (exp_hi) so the final lv
// (which drives the argmax) has no fp16 noise.
__global__ __launch_bounds__(TPB, 4) void k_sink(
    const float* __restrict__ W, float* __restrict__ P, float* __restrict__ H,
    double* __restrict__ part,   // NBLK*NN doubles (8 MiB); fp32-aliased for t<19
    double* __restrict__ colacc) // NN doubles
{
    auto grid = cooperative_groups::this_grid();
    extern __shared__ char smem[];
    __half* Eh    = (__half*)(smem + EH_OFF);
    float*  vbuf  = (float*) (smem + VB_OFF);
    double* wred  = (double*)(smem + WRED_OFF);
    double* u_lds = (double*)(smem + U_OFF);
    float*  partF = (float*)part;

    const int tid = threadIdx.x;
    const int l   = tid & 63;
    const int w   = tid >> 6;        // wave id == local row id
    const int b   = blockIdx.x;

    // ---- setup: Eh[w][:] = fp16(exp(W[row])), u = 1 ----
    {
        const float4* wp = (const float4*)(W + (size_t)(b * ROWS + w) * NN) + l;
        #pragma unroll
        for (int k = 0; k < 16; ++k) {
            float4 x = wp[k * 64];
            U8 p;
            p.h[0] = __floats2half2_rn(expf(x.x), expf(x.y));
            p.h[1] = __floats2half2_rn(expf(x.z), expf(x.w));
            *(ushort4*)(Eh + w * NN + 4 * (l + 64 * k)) = p.s;   // 8 B/lane, contiguous
        }
        if (tid < ROWS) u_lds[tid] = 1.0;
    }
    __syncthreads();

    for (int t = 0; t < NITER; ++t) {
        // ---------- phase C: partial column sums over this block's 16 rows ----------
        const int c0 = tid * 4;               // thread owns cols c0..c0+3
        if (t < NITER - 1) {
            double a0 = 0, a1 = 0, a2 = 0, a3 = 0;
            #pragma unroll
            for (int i = 0; i < ROWS; ++i) {
                U8 e; e.s = *(const ushort4*)(Eh + i * NN + c0);  // conflict-free
                double uu = u_lds[i];                              // LDS broadcast
                float2 f01 = __half22float2(e.h[0]);
                float2 f23 = __half22float2(e.h[1]);
                a0 = fma((double)f01.x, uu, a0);
                a1 = fma((double)f01.y, uu, a1);
                a2 = fma((double)f23.x, uu, a2);
                a3 = fma((double)f23.y, uu, a3);
            }
            float4 pv = make_float4((float)a0, (float)a1, (float)a2, (float)a3);
            *(float4*)(partF + (size_t)b * NN + c0) = pv;          // 1 KB/wave, coalesced
        } else {
            // high-precision last col pass: recompute E from W (L3-resident) in fp64
            double a0 = 0, a1 = 0, a2 = 0, a3 = 0;
            #pragma unroll 4
            for (int i = 0; i < ROWS; ++i) {
                float4 x = *(const float4*)(W + (size_t)(b * ROWS + i) * NN + c0);
                double uu = u_lds[i];
                a0 = fma(exp_hi((double)x.x), uu, a0);
                a1 = fma(exp_hi((double)x.y), uu, a1);
                a2 = fma(exp_hi((double)x.z), uu, a2);
                a3 = fma(exp_hi((double)x.w), uu, a3);
            }
            double2 d01; d01.x = a0; d01.y = a1;
            double2 d23; d23.x = a2; d23.y = a3;
            *(double2*)(part + (size_t)b * NN + c0)     = d01;
            *(double2*)(part + (size_t)b * NN + c0 + 2) = d23;
        }
        grid.sync();

        // ---------- phase D: reduce 256 partials for block's 16 columns ----------
        {
            const int c  = (b << 4) + (tid & 15);
            const int r0 = tid >> 4;                   // 0..63
            double s = 0.0;
            if (t < NITER - 1) {
                #pragma unroll
                for (int k = 0; k < 4; ++k)
                    s += (double)partF[(size_t)(r0 + 64 * k) * NN + c]; // 64B-line coalesced
            } else {
                #pragma unroll
                for (int k = 0; k < 4; ++k)
                    s += part[(size_t)(r0 + 64 * k) * NN + c];
            }
            s += __shfl_xor(s, 16, 64);                // reduce r-subgroups in-wave
            s += __shfl_xor(s, 32, 64);
            if (l < 16) wred[w * 16 + l] = s;          // 16-row partial per wave
        }
        __syncthreads();
        if (tid < 64) {                                // wave 0 finishes 16 cols
            const int c2 = l & 15, g = l >> 4;
            double s2 = wred[g * 16 + c2] + wred[(g + 4) * 16 + c2]
                      + wred[(g + 8) * 16 + c2] + wred[(g + 12) * 16 + c2];
            s2 += __shfl_xor(s2, 16, 64);
            s2 += __shfl_xor(s2, 32, 64);
            if (l < 16) colacc[(b << 4) + l] = s2;
        }
        grid.sync();

        // ---------- phase R: u_i = 1 / sum_j E_ij * v_j (u stays block-local) ----------
        #pragma unroll 4
        for (int j = tid; j < NN; j += TPB)
            vbuf[j] = (float)(1.0 / colacc[j]);        // 32 KB L2/LLC read per block
        __syncthreads();
        {
            double a0 = 0, a1 = 0, a2 = 0, a3 = 0;
            #pragma unroll
            for (int k = 0; k < 8; ++k) {
                const int cc = 512 * k + 8 * l;
                U16 e; e.u = *(const uint4*)(Eh + w * NN + cc);     // b128, conflict-free
                float4 va = *(const float4*)(vbuf + cc);
                float4 vb = *(const float4*)(vbuf + cc + 4);
                float2 f0 = __half22float2(e.h[0]);
                float2 f1 = __half22float2(e.h[1]);
                float2 f2 = __half22float2(e.h[2]);
                float2 f3 = __half22float2(e.h[3]);
                a0 = fma((double)f0.x, (double)va.x, a0);
                a1 = fma((double)f0.y, (double)va.y, a1);
                a2 = fma((double)f1.x, (double)va.z, a2);
                a3 = fma((double)f1.y, (double)va.w, a3);
                a0 = fma((double)f2.x, (double)vb.x, a0);
                a1 = fma((double)f2.y, (double)vb.y, a1);
                a2 = fma((double)f3.x, (double)vb.z, a2);
                a3 = fma((double)f3.y, (double)vb.w, a3);
            }
            double acc = (a0 + a1) + (a2 + a3);
            #pragma unroll
            for (int off = 32; off > 0; off >>= 1)
                acc += __shfl_xor(acc, off, 64);
            if (l == 0) u_lds[w] = 1.0 / acc;
        }
        __syncthreads();   // publish u_lds for next C (block-local only)
    }

    // ---------- final: P = exp(W + lv + lu); H = one-hot(argmax(W + lv)) ----------
    double* lv = (double*)smem;                        // alias Eh (E no longer needed)
    #pragma unroll 4
    for (int j = tid; j < NN; j += TPB) lv[j] = -log(colacc[j]);
    __syncthreads();
    {
        const size_t i = (size_t)(b * ROWS + w);
        const float4* wp = (const float4*)(W + i * NN) + l;
        float4* pp = (float4*)(P + i * NN) + l;
        float4* hp = (float4*)(H + i * NN) + l;
        const double lu = log(u_lds[w]);

        double besty = -1e300;
        int bestj = 0;
        #pragma unroll 4
        for (int k = 0; k < 16; ++k) {
            float4 x = wp[k * 64];
            int jb = k * 256 + l * 4;
            double y0 = (double)x.x + lv[jb + 0];
            double y1 = (double)x.y + lv[jb + 1];
            double y2 = (double)x.z + lv[jb + 2];
            double y3 = (double)x.w + lv[jb + 3];
            float4 pv;
            pv.x = expf((float)(y0 + lu));
            pv.y = expf((float)(y1 + lu));
            pv.z = expf((float)(y2 + lu));
            pv.w = expf((float)(y3 + lu));
            pp[k * 64] = pv;
            if (y0 > besty) { besty = y0; bestj = jb + 0; }   // strict > keeps first index
            if (y1 > besty) { besty = y1; bestj = jb + 1; }
            if (y2 > besty) { besty = y2; bestj = jb + 2; }
            if (y3 > besty) { besty = y3; bestj = jb + 3; }
        }
        for (int off = 32; off > 0; off >>= 1) {
            double oy = __shfl_xor(besty, off, 64);
            int    oj = __shfl_xor(bestj, off, 64);
            if (oy > besty || (oy == besty && oj < bestj)) { besty = oy; bestj = oj; }
        }
        #pragma unroll 4
        for (int k = 0; k < 16; ++k) {
            int jb = k * 256 + l * 4;
            float4 hv;
            hv.x = (jb + 0 == bestj) ? 1.0f : 0.0f;
            hv.y = (jb + 1 == bestj) ? 1.0f : 0.0f;
            hv.z = (jb + 2 == bestj) ? 1.0f : 0.0f;
            hv.w = (jb + 3 == bestj) ? 1.0f : 0.0f;
            hp[k * 64] = hv;
        }
    }
}

extern "C" void kernel_launch(void* const* d_in, const int* in_sizes, int n_in,
                              void* d_out, int out_size, void* d_ws, size_t ws_size,
                              hipStream_t stream) {
    const float* W = (const float*)d_in[0];
    float* P = (float*)d_out;                     // P_hat
    float* H = P + (size_t)NN * NN;               // P_hat_hard (one-hot numerically)

    double* part   = (double*)d_ws;               // 8 MiB (fp32-aliased for t<19)
    double* colacc = part + (size_t)NBLK * NN;    // 32 KB

    static bool attr_done = false;
    if (!attr_done) {
        hipFuncSetAttribute((const void*)k_sink,
                            hipFuncAttributeMaxDynamicSharedMemorySize, SMEM_BYTES);
        attr_done = true;
    }

    void* args[] = {(void*)&W, (void*)&P, (void*)&H, (void*)&part, (void*)&colacc};
    hipLaunchCooperativeKernel((const void*)k_sink, dim3(NBLK), dim3(TPB),
                               args, SMEM_BYTES, stream);
}

// Round 2
// 685.431 us; speedup vs baseline: 2.2169x; 2.2169x over previous
//
#include <hip/hip_runtime.h>
#include <hip/hip_fp16.h>
#include <math.h>

#define NN    4096
#define NITER 20
#define TPB   1024
#define NBLK  256     // == CU count; 1 block/CU (forced by LDS)
#define ROWS  16      // rows of E per block

// ---- dynamic LDS layout (total 149632 B <= 160 KiB/CU) ----
#define EH_OFF    0        // __half Eh[16][4096]           = 131072 B
#define VB_OFF    131072   // float  vbuf[4096]             =  16384 B
#define WRED_OFF  147456   // double wred[16][16]           =   2048 B
#define U_OFF     149504   // double u_lds[16]              =    128 B
#define SMEM_BYTES 149632
// final phase aliases lv[4096] (double, 32 KB) onto Eh space.

// exp of a double argument with fp32 exp + first-order fp64 correction.
__device__ __forceinline__ double exp_hi(double x) {
    float xf = (float)x;
    double dl = x - (double)xf;
    double e = (double)expf(xf);
    return fma(e, dl, e);
}

union U8 { ushort4 s; __half2 h[2]; };   // 8 B = 4 halves

// Relaxed agent-scope accessors: execute at the coherent point (LLC), bypass
// the non-coherent per-XCD L2, and emit NO cache-maintenance instructions.
__device__ __forceinline__ void st_af64(double* p, double v) {
    __hip_atomic_store(p, v, __ATOMIC_RELAXED, __HIP_MEMORY_SCOPE_AGENT);
}
__device__ __forceinline__ double ld_af64(const double* p) {
    return __hip_atomic_load(p, __ATOMIC_RELAXED, __HIP_MEMORY_SCOPE_AGENT);
}

// Lightweight grid barrier: NO acq/rel fences (ROCm's grid.sync does agent-scope
// acq_rel -> L2 writeback+invalidate on every sync = the measured ~32 us/sync).
// Safe because ALL cross-block data moves via relaxed agent-scope atomics (LLC),
// and __syncthreads drains vmcnt (stores complete at coherence point) pre-arrival.
__device__ __forceinline__ void gbar(unsigned* cnt, unsigned* rel, unsigned gen) {
    asm volatile("" ::: "memory");
    __syncthreads();                       // all waves drained their stores
    if (threadIdx.x == 0) {
        unsigned prev = __hip_atomic_fetch_add(cnt, 1u, __ATOMIC_RELAXED,
                                               __HIP_MEMORY_SCOPE_AGENT);
        if (prev == gen * (unsigned)NBLK - 1u) {
            __hip_atomic_store(rel, gen, __ATOMIC_RELAXED, __HIP_MEMORY_SCOPE_AGENT);
        } else {
            while (__hip_atomic_load(rel, __ATOMIC_RELAXED,
                                     __HIP_MEMORY_SCOPE_AGENT) < gen)
                __builtin_amdgcn_s_sleep(8);
        }
    }
    __syncthreads();
    asm volatile("" ::: "memory");
}

__global__ void k_binit(unsigned* cnt, unsigned* rel) {
    if (threadIdx.x == 0) {
        __hip_atomic_store(cnt, 0u, __ATOMIC_RELAXED, __HIP_MEMORY_SCOPE_AGENT);
        __hip_atomic_store(rel, 0u, __ATOMIC_RELAXED, __HIP_MEMORY_SCOPE_AGENT);
    }
}

// One persistent cooperative kernel: E (fp16) lives in LDS for all 20
// Sinkhorn iterations. Per iteration:
//   C: partial col sums (block's 16 rows) -> part[b][j]  (fp64, agent atomics)
//   gbar
//   D: reduce 256 partials for block's 16 cols -> colacc[j]
//   gbar
//   R: v = 1/colacc staged in LDS; per-wave row sums -> u (block-local LDS)
// Last C-pass (t=19) recomputes E from W in fp64 (exp_hi) so the final lv
// (which drives the argmax) has no fp16 noise.
__global__ __launch_bounds__(TPB, 4) void k_sink(
    const float* __restrict__ W, float* __restrict__ P, float* __restrict__ H,
    double* __restrict__ part,   // NBLK*NN fp64 (8 MiB, LLC-resident)
    double* __restrict__ colacc, // NN fp64
    unsigned* __restrict__ cnt, unsigned* __restrict__ rel)
{
    extern __shared__ char smem[];
    __half* Eh    = (__half*)(smem + EH_OFF);
    float*  vbuf  = (float*) (smem + VB_OFF);
    double* wred  = (double*)(smem + WRED_OFF);
    double* u_lds = (double*)(smem + U_OFF);

    const int tid = threadIdx.x;
    const int l   = tid & 63;
    const int w   = tid >> 6;        // wave id == local row id
    const int b   = blockIdx.x;
    unsigned gen  = 0;

    // ---- setup: Eh[w][:] = fp16(exp(W[row])), u = 1 ----
    {
        const float4* wp = (const float4*)(W + (size_t)(b * ROWS + w) * NN) + l;
        #pragma unroll
        for (int k = 0; k < 16; ++k) {
            float4 x = wp[k * 64];
            U8 p;
            p.h[0] = __floats2half2_rn(expf(x.x), expf(x.y));
            p.h[1] = __floats2half2_rn(expf(x.z), expf(x.w));
            *(ushort4*)(Eh + w * NN + 4 * (l + 64 * k)) = p.s;   // 8 B/lane, contiguous
        }
        if (tid < ROWS) u_lds[tid] = 1.0;
    }
    __syncthreads();

    for (int t = 0; t < NITER; ++t) {
        // ---------- phase C: partial column sums over this block's 16 rows ----------
        const int c0 = tid * 4;               // thread owns cols c0..c0+3
        double a0 = 0, a1 = 0, a2 = 0, a3 = 0;
        if (t < NITER - 1) {
            #pragma unroll
            for (int i = 0; i < ROWS; ++i) {
                U8 e; e.s = *(const ushort4*)(Eh + i * NN + c0);  // 8 B/lane, conflict-free
                double uu = u_lds[i];                              // LDS broadcast
                float2 f01 = __half22float2(e.h[0]);
                float2 f23 = __half22float2(e.h[1]);
                a0 = fma((double)f01.x, uu, a0);
                a1 = fma((double)f01.y, uu, a1);
                a2 = fma((double)f23.x, uu, a2);
                a3 = fma((double)f23.y, uu, a3);
            }
        } else {
            // high-precision last col pass: recompute E from W (LLC-resident) in fp64
            #pragma unroll 4
            for (int i = 0; i < ROWS; ++i) {
                float4 x = *(const float4*)(W + (size_t)(b * ROWS + i) * NN + c0);
                double uu = u_lds[i];
                a0 = fma(exp_hi((double)x.x), uu, a0);
                a1 = fma(exp_hi((double)x.y), uu, a1);
                a2 = fma(exp_hi((double)x.z), uu, a2);
                a3 = fma(exp_hi((double)x.w), uu, a3);
            }
        }
        st_af64(&part[(size_t)b * NN + c0 + 0], a0);
        st_af64(&part[(size_t)b * NN + c0 + 1], a1);
        st_af64(&part[(size_t)b * NN + c0 + 2], a2);
        st_af64(&part[(size_t)b * NN + c0 + 3], a3);
        gbar(cnt, rel, ++gen);

        // ---------- phase D: reduce 256 partials for block's 16 columns ----------
        {
            const int c  = (b << 4) + (tid & 15);
            const int r0 = tid >> 4;                   // 0..63
            double s = 0.0;
            #pragma unroll
            for (int k = 0; k < 4; ++k)
                s += ld_af64(&part[(size_t)(r0 + 64 * k) * NN + c]); // 128B/16-lane group
            s += __shfl_xor(s, 16, 64);
            s += __shfl_xor(s, 32, 64);
            if (l < 16) wred[w * 16 + l] = s;          // wave-w partial (16 rows)
        }
        __syncthreads();
        if (tid < 64) {                                // wave 0 finishes 16 cols
            const int c2 = l & 15, g = l >> 4;
            double s2 = wred[g * 16 + c2] + wred[(g + 4) * 16 + c2]
                      + wred[(g + 8) * 16 + c2] + wred[(g + 12) * 16 + c2];
            s2 += __shfl_xor(s2, 16, 64);
            s2 += __shfl_xor(s2, 32, 64);
            if (l < 16) st_af64(&colacc[(b << 4) + l], s2);
        }
        gbar(cnt, rel, ++gen);

        // ---------- phase R: u_i = 1 / sum_j E_ij * v_j (u stays block-local) ----------
        #pragma unroll
        for (int j = tid; j < NN; j += TPB)
            vbuf[j] = (float)(1.0 / ld_af64(&colacc[j]));
        __syncthreads();
        {
            double a4 = 0, a5 = 0, a6 = 0, a7 = 0;
            #pragma unroll
            for (int k = 0; k < 16; ++k) {
                const int cc = 256 * k + 4 * l;
                U8 e; e.s = *(const ushort4*)(Eh + w * NN + cc);  // 8 B/lane, conflict-free
                float4 vv = *(const float4*)(vbuf + cc);          // 16 B/lane, conflict-free
                float2 f01 = __half22float2(e.h[0]);
                float2 f23 = __half22float2(e.h[1]);
                a4 = fma((double)f01.x, (double)vv.x, a4);
                a5 = fma((double)f01.y, (double)vv.y, a5);
                a6 = fma((double)f23.x, (double)vv.z, a6);
                a7 = fma((double)f23.y, (double)vv.w, a7);
            }
            double acc = (a4 + a5) + (a6 + a7);
            #pragma unroll
            for (int off = 32; off > 0; off >>= 1)
                acc += __shfl_xor(acc, off, 64);
            if (l == 0) u_lds[w] = 1.0 / acc;
        }
        __syncthreads();   // publish u_lds for next C (block-local only)
    }

    // ---------- final: P = exp(W + lv + lu); H = one-hot(argmax(W + lv)) ----------
    double* lv = (double*)smem;                        // alias Eh (E no longer needed)
    #pragma unroll
    for (int j = tid; j < NN; j += TPB) lv[j] = -log(ld_af64(&colacc[j]));
    __syncthreads();
    {
        const size_t i = (size_t)(b * ROWS + w);
        const float2* wp = (const float2*)(W + i * NN) + l;
        float2* pp = (float2*)(P + i * NN) + l;
        float2* hp = (float2*)(H + i * NN) + l;
        const double lu = log(u_lds[w]);

        double besty = -1e300;
        int bestj = 0;
        #pragma unroll 4
        for (int k = 0; k < 32; ++k) {
            float2 x = wp[k * 64];                     // 8 B/lane, 512 B/wave coalesced
            int jb = k * 128 + l * 2;
            double2 lvv = *(const double2*)(lv + jb);  // 16 B/lane, conflict-free
            double y0 = (double)x.x + lvv.x;
            double y1 = (double)x.y + lvv.y;
            float2 pv;
            pv.x = expf((float)(y0 + lu));
            pv.y = expf((float)(y1 + lu));
            pp[k * 64] = pv;
            if (y0 > besty) { besty = y0; bestj = jb + 0; }   // strict > keeps first index
            if (y1 > besty) { besty = y1; bestj = jb + 1; }
        }
        for (int off = 32; off > 0; off >>= 1) {
            double oy = __shfl_xor(besty, off, 64);
            int    oj = __shfl_xor(bestj, off, 64);
            if (oy > besty || (oy == besty && oj < bestj)) { besty = oy; bestj = oj; }
        }
        #pragma unroll 4
        for (int k = 0; k < 32; ++k) {
            int jb = k * 128 + l * 2;
            float2 hv;
            hv.x = (jb + 0 == bestj) ? 1.0f : 0.0f;
            hv.y = (jb + 1 == bestj) ? 1.0f : 0.0f;
            hp[k * 64] = hv;
        }
    }
}

extern "C" void kernel_launch(void* const* d_in, const int* in_sizes, int n_in,
                              void* d_out, int out_size, void* d_ws, size_t ws_size,
                              hipStream_t stream) {
    const float* W = (const float*)d_in[0];
    float* P = (float*)d_out;                     // P_hat
    float* H = P + (size_t)NN * NN;               // P_hat_hard (one-hot numerically)

    double*   part   = (double*)d_ws;             // 8 MiB
    double*   colacc = part + (size_t)NBLK * NN;  // 32 KB
    unsigned* cnt    = (unsigned*)(colacc + NN);
    unsigned* rel    = cnt + 1;

    static bool attr_done = false;
    if (!attr_done) {
        hipFuncSetAttribute((const void*)k_sink,
                            hipFuncAttributeMaxDynamicSharedMemorySize, SMEM_BYTES);
        attr_done = true;
    }

    k_binit<<<1, 64, 0, stream>>>(cnt, rel);

    void* args[] = {(void*)&W, (void*)&P, (void*)&H,
                    (void*)&part, (void*)&colacc, (void*)&cnt, (void*)&rel};
    hipLaunchCooperativeKernel((const void*)k_sink, dim3(NBLK), dim3(TPB),
                               args, SMEM_BYTES, stream);
}

// Round 4
// 590.830 us; speedup vs baseline: 2.5718x; 1.1601x over previous
//
#include <hip/hip_runtime.h>
#include <hip/hip_fp16.h>
#include <math.h>

#define NN    4096
#define NITER 20
#define TPB   1024
#define NBLK  256     // == CU count; 1 block/CU (forced by LDS)
#define ROWS  16      // rows of E per block

// ---- dynamic LDS layout (total 149632 B <= 160 KiB/CU) ----
#define EH_OFF    0        // __half Eh[16][4096]           = 131072 B
#define VB_OFF    131072   // float  vbuf[4096]             =  16384 B
#define WRED_OFF  147456   // double wred[16][16]           =   2048 B
#define U_OFF     149504   // double u_lds[16]              =    128 B
#define SMEM_BYTES 149632
// final phase aliases lv[4096] (double, 32 KB) onto Eh space.

// Native ext-vector types: required for inline-asm "v" constraints (HIP's
// float4 is a struct -> "indirect register inputs" compile error).
typedef float  vf4 __attribute__((ext_vector_type(4)));
typedef double vd2 __attribute__((ext_vector_type(2)));

// exp of a double argument with fp32 exp + first-order fp64 correction.
__device__ __forceinline__ double exp_hi(double x) {
    float xf = (float)x;
    double dl = x - (double)xf;
    double e = (double)expf(xf);
    return fma(e, dl, e);
}

union U8 { ushort4 s; __half2 h[2]; };   // 8 B = 4 halves
union DF { double d[2]; vf4 f; };        // fp64 pair <-> 16B asm payload

// ---- device-scope PLAIN memory ops (sc1: bypass L1+per-XCD L2, serve at LLC).
// Replaces 8B agent atomics: full 16B width, full 32B-sector utilization, and
// batched issue with ONE waitcnt instead of per-op serialization.
__device__ __forceinline__ void st_dev_f4(float* p, vf4 v) {
    asm volatile("global_store_dwordx4 %0, %1, off sc1" :: "v"(p), "v"(v) : "memory");
}
__device__ __forceinline__ void st_dev_d2(double* p, double a, double b) {
    DF u; u.d[0] = a; u.d[1] = b;
    asm volatile("global_store_dwordx4 %0, %1, off sc1" :: "v"(p), "v"(u.f) : "memory");
}
__device__ __forceinline__ void st_dev_d1(double* p, double v) {
    asm volatile("global_store_dwordx2 %0, %1, off sc1" :: "v"(p), "v"(v) : "memory");
}
__device__ __forceinline__ void ld4_dev_f(const float* p0, const float* p1,
                                          const float* p2, const float* p3,
                                          float& a0, float& a1, float& a2, float& a3) {
    asm volatile(
        "global_load_dword %0, %4, off sc1\n\t"
        "global_load_dword %1, %5, off sc1\n\t"
        "global_load_dword %2, %6, off sc1\n\t"
        "global_load_dword %3, %7, off sc1\n\t"
        "s_waitcnt vmcnt(0)"
        : "=&v"(a0), "=&v"(a1), "=&v"(a2), "=&v"(a3)
        : "v"(p0), "v"(p1), "v"(p2), "v"(p3) : "memory");
}
__device__ __forceinline__ void ld4_dev_d(const double* p0, const double* p1,
                                          const double* p2, const double* p3,
                                          double& a0, double& a1, double& a2, double& a3) {
    asm volatile(
        "global_load_dwordx2 %0, %4, off sc1\n\t"
        "global_load_dwordx2 %1, %5, off sc1\n\t"
        "global_load_dwordx2 %2, %6, off sc1\n\t"
        "global_load_dwordx2 %3, %7, off sc1\n\t"
        "s_waitcnt vmcnt(0)"
        : "=&v"(a0), "=&v"(a1), "=&v"(a2), "=&v"(a3)
        : "v"(p0), "v"(p1), "v"(p2), "v"(p3) : "memory");
}
__device__ __forceinline__ void ld2_dev_f4(const double* p0, const double* p1,
                                           vf4& x, vf4& y) {
    asm volatile(
        "global_load_dwordx4 %0, %2, off sc1\n\t"
        "global_load_dwordx4 %1, %3, off sc1\n\t"
        "s_waitcnt vmcnt(0)"
        : "=&v"(x), "=&v"(y)
        : "v"(p0), "v"(p1) : "memory");
}

// Lightweight grid barrier, no cache-maintenance fences (grid.sync's agent-scope
// acq_rel L2 flush was ~21 us/sync). Cross-block data moves via sc1 ops (LLC),
// so only arrival ordering is needed: drain vmcnt (incl. untracked asm stores),
// then count arrivals with relaxed agent atomics.
__device__ __forceinline__ void gbar(unsigned* cnt, unsigned* rel, unsigned gen) {
    asm volatile("s_waitcnt vmcnt(0)" ::: "memory");   // asm stores are untracked
    __syncthreads();
    if (threadIdx.x == 0) {
        unsigned prev = __hip_atomic_fetch_add(cnt, 1u, __ATOMIC_RELAXED,
                                               __HIP_MEMORY_SCOPE_AGENT);
        if (prev == gen * (unsigned)NBLK - 1u) {
            __hip_atomic_store(rel, gen, __ATOMIC_RELAXED, __HIP_MEMORY_SCOPE_AGENT);
        } else {
            while (__hip_atomic_load(rel, __ATOMIC_RELAXED,
                                     __HIP_MEMORY_SCOPE_AGENT) < gen)
                __builtin_amdgcn_s_sleep(1);
        }
    }
    __syncthreads();
    asm volatile("" ::: "memory");
}

__global__ void k_binit(unsigned* cnt, unsigned* rel) {
    if (threadIdx.x == 0) {
        __hip_atomic_store(cnt, 0u, __ATOMIC_RELAXED, __HIP_MEMORY_SCOPE_AGENT);
        __hip_atomic_store(rel, 0u, __ATOMIC_RELAXED, __HIP_MEMORY_SCOPE_AGENT);
    }
}

// Persistent kernel: E (fp16) in LDS for all 20 iterations. Per iteration:
//   C: partial col sums (block's 16 rows) -> part (fp32; fp64 @ t=19)
//   gbar
//   D: reduce 256 partials for block's 16 cols -> colacc
//   gbar
//   R: v = 1/colacc staged in LDS; per-wave row sums -> u (block-local LDS)
// t=19 recomputes E from W in fp64 so the final lv (argmax input) is exact.
__global__ __launch_bounds__(TPB, 4) void k_sink(
    const float* __restrict__ W, float* __restrict__ P, float* __restrict__ H,
    double* __restrict__ part,   // 8 MiB; fp32-aliased for t<19
    double* __restrict__ colacc, // NN fp64
    unsigned* __restrict__ cnt, unsigned* __restrict__ rel)
{
    extern __shared__ char smem[];
    __half* Eh    = (__half*)(smem + EH_OFF);
    float*  vbuf  = (float*) (smem + VB_OFF);
    double* wred  = (double*)(smem + WRED_OFF);
    double* u_lds = (double*)(smem + U_OFF);
    float*  partF = (float*)part;

    const int tid = threadIdx.x;
    const int l   = tid & 63;
    const int w   = tid >> 6;        // wave id == local row id
    const int b   = blockIdx.x;
    unsigned gen  = 0;

    // ---- setup: Eh[w][:] = fp16(exp(W[row])), u = 1 ----
    {
        const float4* wp = (const float4*)(W + (size_t)(b * ROWS + w) * NN) + l;
        #pragma unroll
        for (int k = 0; k < 16; ++k) {
            float4 x = wp[k * 64];
            U8 p;
            p.h[0] = __floats2half2_rn(expf(x.x), expf(x.y));
            p.h[1] = __floats2half2_rn(expf(x.z), expf(x.w));
            *(ushort4*)(Eh + w * NN + 4 * (l + 64 * k)) = p.s;   // 8 B/lane, contiguous
        }
        if (tid < ROWS) u_lds[tid] = 1.0;
    }
    __syncthreads();

    for (int t = 0; t < NITER; ++t) {
        // ---------- phase C: partial column sums over this block's 16 rows ----------
        const int c0 = tid * 4;               // thread owns cols c0..c0+3
        double a0 = 0, a1 = 0, a2 = 0, a3 = 0;
        if (t < NITER - 1) {
            #pragma unroll
            for (int i = 0; i < ROWS; ++i) {
                U8 e; e.s = *(const ushort4*)(Eh + i * NN + c0);  // 8 B/lane, conflict-free
                double uu = u_lds[i];                              // LDS broadcast
                float2 f01 = __half22float2(e.h[0]);
                float2 f23 = __half22float2(e.h[1]);
                a0 = fma((double)f01.x, uu, a0);
                a1 = fma((double)f01.y, uu, a1);
                a2 = fma((double)f23.x, uu, a2);
                a3 = fma((double)f23.y, uu, a3);
            }
            // one full-width 16B store, thread-contiguous -> full 32B sectors
            vf4 pv = {(float)a0, (float)a1, (float)a2, (float)a3};
            st_dev_f4(partF + (size_t)b * NN + c0, pv);
        } else {
            // high-precision last col pass: recompute E from W (LLC-resident) in fp64
            #pragma unroll 4
            for (int i = 0; i < ROWS; ++i) {
                float4 x = *(const float4*)(W + (size_t)(b * ROWS + i) * NN + c0);
                double uu = u_lds[i];
                a0 = fma(exp_hi((double)x.x), uu, a0);
                a1 = fma(exp_hi((double)x.y), uu, a1);
                a2 = fma(exp_hi((double)x.z), uu, a2);
                a3 = fma(exp_hi((double)x.w), uu, a3);
            }
            st_dev_d2(part + (size_t)b * NN + c0,     a0, a1);
            st_dev_d2(part + (size_t)b * NN + c0 + 2, a2, a3);
        }
        gbar(cnt, rel, ++gen);

        // ---------- phase D: reduce 256 partials for block's 16 columns ----------
        {
            const int c  = (b << 4) + (tid & 15);
            const int r0 = tid >> 4;                   // 0..63
            double s;
            if (t < NITER - 1) {
                float f0, f1, f2, f3;                  // batched issue, one waitcnt
                ld4_dev_f(&partF[(size_t)(r0 +   0) * NN + c],
                          &partF[(size_t)(r0 +  64) * NN + c],
                          &partF[(size_t)(r0 + 128) * NN + c],
                          &partF[(size_t)(r0 + 192) * NN + c], f0, f1, f2, f3);
                s = ((double)f0 + (double)f1) + ((double)f2 + (double)f3);
            } else {
                double d0, d1, d2, d3;
                ld4_dev_d(&part[(size_t)(r0 +   0) * NN + c],
                          &part[(size_t)(r0 +  64) * NN + c],
                          &part[(size_t)(r0 + 128) * NN + c],
                          &part[(size_t)(r0 + 192) * NN + c], d0, d1, d2, d3);
                s = (d0 + d1) + (d2 + d3);
            }
            s += __shfl_xor(s, 16, 64);
            s += __shfl_xor(s, 32, 64);
            if (l < 16) wred[w * 16 + l] = s;          // wave-w partial (16 rows)
        }
        __syncthreads();
        if (tid < 64) {                                // wave 0 finishes 16 cols
            const int c2 = l & 15, g = l >> 4;
            double s2 = wred[g * 16 + c2] + wred[(g + 4) * 16 + c2]
                      + wred[(g + 8) * 16 + c2] + wred[(g + 12) * 16 + c2];
            s2 += __shfl_xor(s2, 16, 64);
            s2 += __shfl_xor(s2, 32, 64);
            if (l < 16) st_dev_d1(&colacc[(b << 4) + l], s2);
        }
        gbar(cnt, rel, ++gen);

        // ---------- phase R: u_i = 1 / sum_j E_ij * v_j (u stays block-local) ----------
        {
            const int j0 = tid * 4;
            DF x, y;
            ld2_dev_f4(colacc + j0, colacc + j0 + 2, x.f, y.f);   // 32 B/thread, contiguous
            float4 vv;
            vv.x = (float)(1.0 / x.d[0]);
            vv.y = (float)(1.0 / x.d[1]);
            vv.z = (float)(1.0 / y.d[0]);
            vv.w = (float)(1.0 / y.d[1]);
            *(float4*)(vbuf + j0) = vv;
        }
        __syncthreads();
        {
            double a4 = 0, a5 = 0, a6 = 0, a7 = 0;
            #pragma unroll
            for (int k = 0; k < 16; ++k) {
                const int cc = 256 * k + 4 * l;
                U8 e; e.s = *(const ushort4*)(Eh + w * NN + cc);  // 8 B/lane, conflict-free
                float4 vv = *(const float4*)(vbuf + cc);          // 16 B/lane, conflict-free
                float2 f01 = __half22float2(e.h[0]);
                float2 f23 = __half22float2(e.h[1]);
                a4 = fma((double)f01.x, (double)vv.x, a4);
                a5 = fma((double)f01.y, (double)vv.y, a5);
                a6 = fma((double)f23.x, (double)vv.z, a6);
                a7 = fma((double)f23.y, (double)vv.w, a7);
            }
            double acc = (a4 + a5) + (a6 + a7);
            #pragma unroll
            for (int off = 32; off > 0; off >>= 1)
                acc += __shfl_xor(acc, off, 64);
            if (l == 0) u_lds[w] = 1.0 / acc;
        }
        __syncthreads();   // publish u_lds for next C (block-local only)
    }

    // ---------- final: P = exp(W + lv + lu); H = one-hot(argmax(W + lv)) ----------
    double* lv = (double*)smem;                        // alias Eh (E no longer needed)
    {
        const int j0 = tid * 4;
        DF x, y;
        ld2_dev_f4(colacc + j0, colacc + j0 + 2, x.f, y.f);
        lv[j0 + 0] = -log(x.d[0]);
        lv[j0 + 1] = -log(x.d[1]);
        lv[j0 + 2] = -log(y.d[0]);
        lv[j0 + 3] = -log(y.d[1]);
    }
    __syncthreads();
    {
        const size_t i = (size_t)(b * ROWS + w);
        const float2* wp = (const float2*)(W + i * NN) + l;
        float2* pp = (float2*)(P + i * NN) + l;
        float2* hp = (float2*)(H + i * NN) + l;
        const double lu = log(u_lds[w]);

        double besty = -1e300;
        int bestj = 0;
        #pragma unroll 4
        for (int k = 0; k < 32; ++k) {
            float2 x = wp[k * 64];                     // 8 B/lane, 512 B/wave coalesced
            int jb = k * 128 + l * 2;
            double2 lvv = *(const double2*)(lv + jb);  // 16 B/lane, conflict-free
            double y0 = (double)x.x + lvv.x;
            double y1 = (double)x.y + lvv.y;
            float2 pv;
            pv.x = expf((float)(y0 + lu));
            pv.y = expf((float)(y1 + lu));
            pp[k * 64] = pv;
            if (y0 > besty) { besty = y0; bestj = jb + 0; }   // strict > keeps first index
            if (y1 > besty) { besty = y1; bestj = jb + 1; }
        }
        for (int off = 32; off > 0; off >>= 1) {
            double oy = __shfl_xor(besty, off, 64);
            int    oj = __shfl_xor(bestj, off, 64);
            if (oy > besty || (oy == besty && oj < bestj)) { besty = oy; bestj = oj; }
        }
        #pragma unroll 4
        for (int k = 0; k < 32; ++k) {
            int jb = k * 128 + l * 2;
            float2 hv;
            hv.x = (jb + 0 == bestj) ? 1.0f : 0.0f;
            hv.y = (jb + 1 == bestj) ? 1.0f : 0.0f;
            hp[k * 64] = hv;
        }
    }
}

extern "C" void kernel_launch(void* const* d_in, const int* in_sizes, int n_in,
                              void* d_out, int out_size, void* d_ws, size_t ws_size,
                              hipStream_t stream) {
    const float* W = (const float*)d_in[0];
    float* P = (float*)d_out;                     // P_hat
    float* H = P + (size_t)NN * NN;               // P_hat_hard (one-hot numerically)

    double*   part   = (double*)d_ws;             // 8 MiB
    double*   colacc = part + (size_t)NBLK * NN;  // 32 KB
    unsigned* cnt    = (unsigned*)(colacc + NN);
    unsigned* rel    = cnt + 1;

    static bool attr_done = false;
    if (!attr_done) {
        (void)hipFuncSetAttribute((const void*)k_sink,
                                  hipFuncAttributeMaxDynamicSharedMemorySize,
                                  SMEM_BYTES);
        attr_done = true;
    }

    k_binit<<<1, 64, 0, stream>>>(cnt, rel);

    void* args[] = {(void*)&W, (void*)&P, (void*)&H,
                    (void*)&part, (void*)&colacc, (void*)&cnt, (void*)&rel};
    (void)hipLaunchCooperativeKernel((const void*)k_sink, dim3(NBLK), dim3(TPB),
                                     args, SMEM_BYTES, stream);
}

// Round 6
// 522.330 us; speedup vs baseline: 2.9091x; 1.1311x over previous
//
#include <hip/hip_runtime.h>
#include <hip/hip_fp16.h>
#include <math.h>

#define NN    4096
#define NITER 20
#define TPB   1024
#define NBLK  256     // == CU count; 1 block/CU (forced by LDS)
#define ROWS  16      // rows of E per block

// ---- dynamic LDS layout (total 149632 B <= 160 KiB/CU) ----
#define EH_OFF    0        // __half Eh[16][4096]           = 131072 B
#define VB_OFF    131072   // float  vbuf[4096]             =  16384 B
#define WRED_OFF  147456   // double wred[16][16]           =   2048 B
#define U_OFF     149504   // double u_lds[16]              =    128 B
#define SMEM_BYTES 149632
// final phase aliases lv[4096] (double, 32 KB) onto Eh space.

// Native ext-vector types: required for inline-asm "v" constraints (HIP's
// float4 is a struct -> "indirect register inputs" compile error).
typedef float    vf4 __attribute__((ext_vector_type(4)));
typedef unsigned vu4 __attribute__((ext_vector_type(4)));

// exp of a double argument with fp32 exp + first-order fp64 correction.
__device__ __forceinline__ double exp_hi(double x) {
    float xf = (float)x;
    double dl = x - (double)xf;
    double e = (double)expf(xf);
    return fma(e, dl, e);
}

union U8 { ushort4 s; __half2 h[2]; };   // 8 B = 4 halves
union DF { double d[2]; vf4 f; };        // fp64 pair <-> 16B asm payload

// ---- device-scope PLAIN memory ops (sc1: bypass L1+per-XCD L2, serve at LLC).
__device__ __forceinline__ void st_dev_f4(float* p, vf4 v) {
    asm volatile("global_store_dwordx4 %0, %1, off sc1" :: "v"(p), "v"(v) : "memory");
}
__device__ __forceinline__ void st_dev_d2(double* p, double a, double b) {
    DF u; u.d[0] = a; u.d[1] = b;
    asm volatile("global_store_dwordx4 %0, %1, off sc1" :: "v"(p), "v"(u.f) : "memory");
}
__device__ __forceinline__ void st_dev_d1(double* p, double v) {
    asm volatile("global_store_dwordx2 %0, %1, off sc1" :: "v"(p), "v"(v) : "memory");
}
__device__ __forceinline__ void st_dev_u32(unsigned* p, unsigned v) {
    asm volatile("global_store_dword %0, %1, off sc1" :: "v"(p), "v"(v) : "memory");
}
__device__ __forceinline__ vu4 ld_dev_u32x4(const unsigned* p) {
    vu4 r;
    asm volatile("global_load_dwordx4 %0, %1, off sc1\n\ts_waitcnt vmcnt(0)"
                 : "=v"(r) : "v"(p) : "memory");
    return r;
}
__device__ __forceinline__ void ld4_dev_f(const float* p0, const float* p1,
                                          const float* p2, const float* p3,
                                          float& a0, float& a1, float& a2, float& a3) {
    asm volatile(
        "global_load_dword %0, %4, off sc1\n\t"
        "global_load_dword %1, %5, off sc1\n\t"
        "global_load_dword %2, %6, off sc1\n\t"
        "global_load_dword %3, %7, off sc1\n\t"
        "s_waitcnt vmcnt(0)"
        : "=&v"(a0), "=&v"(a1), "=&v"(a2), "=&v"(a3)
        : "v"(p0), "v"(p1), "v"(p2), "v"(p3) : "memory");
}
__device__ __forceinline__ void ld4_dev_d(const double* p0, const double* p1,
                                          const double* p2, const double* p3,
                                          double& a0, double& a1, double& a2, double& a3) {
    asm volatile(
        "global_load_dwordx2 %0, %4, off sc1\n\t"
        "global_load_dwordx2 %1, %5, off sc1\n\t"
        "global_load_dwordx2 %2, %6, off sc1\n\t"
        "global_load_dwordx2 %3, %7, off sc1\n\t"
        "s_waitcnt vmcnt(0)"
        : "=&v"(a0), "=&v"(a1), "=&v"(a2), "=&v"(a3)
        : "v"(p0), "v"(p1), "v"(p2), "v"(p3) : "memory");
}
__device__ __forceinline__ void ld2_dev_f4(const double* p0, const double* p1,
                                           vf4& x, vf4& y) {
    asm volatile(
        "global_load_dwordx4 %0, %2, off sc1\n\t"
        "global_load_dwordx4 %1, %3, off sc1\n\t"
        "s_waitcnt vmcnt(0)"
        : "=&v"(x), "=&v"(y)
        : "v"(p0), "v"(p1) : "memory");
}

// ---- RMW-free "all-check" grid barrier.
// Replaces the fetch_add barrier (~7 us: 256 serialized same-address LLC RMWs
// + release publish + poll). Each block STORES its generation to its own slot
// (parallel, no serialization); wave 0 polls all 256 slots with ONE
// dwordx4/lane until all >= gen.
// Deadlock-free: gens are monotone; a block passes barrier g only after all
// slots >= g, so max skew is one phase and ">= gen" absorbs it. The sc1
// store->sc1 load path is the same one the data plane used in the previous
// PASSING run (absmax 1.9e-6), so slot visibility across XCDs is proven.
__device__ __forceinline__ void gbar(unsigned* arrive, unsigned gen) {
    asm volatile("s_waitcnt vmcnt(0)" ::: "memory");   // data stores visible first
    __syncthreads();                                   // all waves in block done
    const int tid = threadIdx.x;
    if (tid == 0) st_dev_u32(arrive + blockIdx.x, gen);
    if (tid < 64) {
        for (;;) {
            vu4 a = ld_dev_u32x4(arrive + 4 * tid);    // 64 lanes x 4 = all 256 slots
            bool ok = a.x >= gen && a.y >= gen && a.z >= gen && a.w >= gen;
            if (__all(ok)) break;
            __builtin_amdgcn_s_sleep(2);
        }
    }
    __syncthreads();
    asm volatile("" ::: "memory");
}

__global__ void k_binit(unsigned* arrive) {
    int i = threadIdx.x;
    if (i < NBLK) arrive[i] = 0u;   // end-of-kernel implicit release publishes this
}

// Persistent kernel: E (fp16) in LDS for all 20 iterations. Per iteration:
//   C: partial col sums (block's 16 rows) -> part (fp32; fp64 @ t=19)
//   gbar
//   D: reduce 256 partials for block's 16 cols -> colacc
//   gbar
//   R: v = 1/colacc staged in LDS; per-wave row sums -> u (block-local LDS)
// t=19 recomputes E from W in fp64 so the final lv (argmax input) is exact.
__global__ __launch_bounds__(TPB, 4) void k_sink(
    const float* __restrict__ W, float* __restrict__ P, float* __restrict__ H,
    double* __restrict__ part,   // 8 MiB; fp32-aliased for t<19
    double* __restrict__ colacc, // NN fp64
    unsigned* __restrict__ arrive)
{
    extern __shared__ char smem[];
    __half* Eh    = (__half*)(smem + EH_OFF);
    float*  vbuf  = (float*) (smem + VB_OFF);
    double* wred  = (double*)(smem + WRED_OFF);
    double* u_lds = (double*)(smem + U_OFF);
    float*  partF = (float*)part;

    const int tid = threadIdx.x;
    const int l   = tid & 63;
    const int w   = tid >> 6;        // wave id == local row id
    const int b   = blockIdx.x;
    unsigned gen  = 0;

    // ---- setup: Eh[w][:] = fp16(exp(W[row])), u = 1 ----
    {
        const float4* wp = (const float4*)(W + (size_t)(b * ROWS + w) * NN) + l;
        #pragma unroll
        for (int k = 0; k < 16; ++k) {
            float4 x = wp[k * 64];
            U8 p;
            p.h[0] = __floats2half2_rn(expf(x.x), expf(x.y));
            p.h[1] = __floats2half2_rn(expf(x.z), expf(x.w));
            *(ushort4*)(Eh + w * NN + 4 * (l + 64 * k)) = p.s;   // 8 B/lane, contiguous
        }
        if (tid < ROWS) u_lds[tid] = 1.0;
    }
    __syncthreads();

    for (int t = 0; t < NITER; ++t) {
        // ---------- phase C: partial column sums over this block's 16 rows ----------
        const int c0 = tid * 4;               // thread owns cols c0..c0+3
        double a0 = 0, a1 = 0, a2 = 0, a3 = 0;
        if (t < NITER - 1) {
            #pragma unroll
            for (int i = 0; i < ROWS; ++i) {
                U8 e; e.s = *(const ushort4*)(Eh + i * NN + c0);  // 8 B/lane, conflict-free
                double uu = u_lds[i];                              // LDS broadcast
                float2 f01 = __half22float2(e.h[0]);
                float2 f23 = __half22float2(e.h[1]);
                a0 = fma((double)f01.x, uu, a0);
                a1 = fma((double)f01.y, uu, a1);
                a2 = fma((double)f23.x, uu, a2);
                a3 = fma((double)f23.y, uu, a3);
            }
            // one full-width 16B store, thread-contiguous -> full 32B sectors
            vf4 pv = {(float)a0, (float)a1, (float)a2, (float)a3};
            st_dev_f4(partF + (size_t)b * NN + c0, pv);
        } else {
            // high-precision last col pass: recompute E from W (LLC-resident) in fp64
            #pragma unroll 4
            for (int i = 0; i < ROWS; ++i) {
                float4 x = *(const float4*)(W + (size_t)(b * ROWS + i) * NN + c0);
                double uu = u_lds[i];
                a0 = fma(exp_hi((double)x.x), uu, a0);
                a1 = fma(exp_hi((double)x.y), uu, a1);
                a2 = fma(exp_hi((double)x.z), uu, a2);
                a3 = fma(exp_hi((double)x.w), uu, a3);
            }
            st_dev_d2(part + (size_t)b * NN + c0,     a0, a1);
            st_dev_d2(part + (size_t)b * NN + c0 + 2, a2, a3);
        }
        gbar(arrive, ++gen);

        // ---------- phase D: reduce 256 partials for block's 16 columns ----------
        {
            const int c  = (b << 4) + (tid & 15);
            const int r0 = tid >> 4;                   // 0..63
            double s;
            if (t < NITER - 1) {
                float f0, f1, f2, f3;                  // batched issue, one waitcnt
                ld4_dev_f(&partF[(size_t)(r0 +   0) * NN + c],
                          &partF[(size_t)(r0 +  64) * NN + c],
                          &partF[(size_t)(r0 + 128) * NN + c],
                          &partF[(size_t)(r0 + 192) * NN + c], f0, f1, f2, f3);
                s = ((double)f0 + (double)f1) + ((double)f2 + (double)f3);
            } else {
                double d0, d1, d2, d3;
                ld4_dev_d(&part[(size_t)(r0 +   0) * NN + c],
                          &part[(size_t)(r0 +  64) * NN + c],
                          &part[(size_t)(r0 + 128) * NN + c],
                          &part[(size_t)(r0 + 192) * NN + c], d0, d1, d2, d3);
                s = (d0 + d1) + (d2 + d3);
            }
            s += __shfl_xor(s, 16, 64);
            s += __shfl_xor(s, 32, 64);
            if (l < 16) wred[w * 16 + l] = s;          // wave-w partial (16 rows)
        }
        __syncthreads();
        if (tid < 64) {                                // wave 0 finishes 16 cols
            const int c2 = l & 15, g = l >> 4;
            double s2 = wred[g * 16 + c2] + wred[(g + 4) * 16 + c2]
                      + wred[(g + 8) * 16 + c2] + wred[(g + 12) * 16 + c2];
            s2 += __shfl_xor(s2, 16, 64);
            s2 += __shfl_xor(s2, 32, 64);
            if (l < 16) st_dev_d1(&colacc[(b << 4) + l], s2);
        }
        gbar(arrive, ++gen);

        // ---------- phase R: u_i = 1 / sum_j E_ij * v_j (u stays block-local) ----------
        {
            const int j0 = tid * 4;
            DF x, y;
            ld2_dev_f4(colacc + j0, colacc + j0 + 2, x.f, y.f);   // 32 B/thread, contiguous
            float4 vv;
            vv.x = (float)(1.0 / x.d[0]);
            vv.y = (float)(1.0 / x.d[1]);
            vv.z = (float)(1.0 / y.d[0]);
            vv.w = (float)(1.0 / y.d[1]);
            *(float4*)(vbuf + j0) = vv;
        }
        __syncthreads();
        {
            double a4 = 0, a5 = 0, a6 = 0, a7 = 0;
            #pragma unroll
            for (int k = 0; k < 16; ++k) {
                const int cc = 256 * k + 4 * l;
                U8 e; e.s = *(const ushort4*)(Eh + w * NN + cc);  // 8 B/lane, conflict-free
                float4 vv = *(const float4*)(vbuf + cc);          // 16 B/lane, conflict-free
                float2 f01 = __half22float2(e.h[0]);
                float2 f23 = __half22float2(e.h[1]);
                a4 = fma((double)f01.x, (double)vv.x, a4);
                a5 = fma((double)f01.y, (double)vv.y, a5);
                a6 = fma((double)f23.x, (double)vv.z, a6);
                a7 = fma((double)f23.y, (double)vv.w, a7);
            }
            double acc = (a4 + a5) + (a6 + a7);
            #pragma unroll
            for (int off = 32; off > 0; off >>= 1)
                acc += __shfl_xor(acc, off, 64);
            if (l == 0) u_lds[w] = 1.0 / acc;
        }
        __syncthreads();   // publish u_lds for next C (block-local only)
    }

    // ---------- final: P = exp(W + lv + lu); H = one-hot(argmax(W + lv)) ----------
    double* lv = (double*)smem;                        // alias Eh (E no longer needed)
    {
        const int j0 = tid * 4;
        DF x, y;
        ld2_dev_f4(colacc + j0, colacc + j0 + 2, x.f, y.f);
        lv[j0 + 0] = -log(x.d[0]);
        lv[j0 + 1] = -log(x.d[1]);
        lv[j0 + 2] = -log(y.d[0]);
        lv[j0 + 3] = -log(y.d[1]);
    }
    __syncthreads();
    {
        const size_t i = (size_t)(b * ROWS + w);
        const float2* wp = (const float2*)(W + i * NN) + l;
        float2* pp = (float2*)(P + i * NN) + l;
        float2* hp = (float2*)(H + i * NN) + l;
        const double lu = log(u_lds[w]);

        double besty = -1e300;
        int bestj = 0;
        #pragma unroll 4
        for (int k = 0; k < 32; ++k) {
            float2 x = wp[k * 64];                     // 8 B/lane, 512 B/wave coalesced
            int jb = k * 128 + l * 2;
            double2 lvv = *(const double2*)(lv + jb);  // 16 B/lane, conflict-free
            double y0 = (double)x.x + lvv.x;
            double y1 = (double)x.y + lvv.y;
            float2 pv;
            pv.x = expf((float)(y0 + lu));
            pv.y = expf((float)(y1 + lu));
            pp[k * 64] = pv;
            if (y0 > besty) { besty = y0; bestj = jb + 0; }   // strict > keeps first index
            if (y1 > besty) { besty = y1; bestj = jb + 1; }
        }
        for (int off = 32; off > 0; off >>= 1) {
            double oy = __shfl_xor(besty, off, 64);
            int    oj = __shfl_xor(bestj, off, 64);
            if (oy > besty || (oy == besty && oj < bestj)) { besty = oy; bestj = oj; }
        }
        #pragma unroll 4
        for (int k = 0; k < 32; ++k) {
            int jb = k * 128 + l * 2;
            float2 hv;
            hv.x = (jb + 0 == bestj) ? 1.0f : 0.0f;
            hv.y = (jb + 1 == bestj) ? 1.0f : 0.0f;
            hp[k * 64] = hv;
        }
    }
}

extern "C" void kernel_launch(void* const* d_in, const int* in_sizes, int n_in,
                              void* d_out, int out_size, void* d_ws, size_t ws_size,
                              hipStream_t stream) {
    const float* W = (const float*)d_in[0];
    float* P = (float*)d_out;                     // P_hat
    float* H = P + (size_t)NN * NN;               // P_hat_hard (one-hot numerically)

    double*   part   = (double*)d_ws;             // 8 MiB
    double*   colacc = part + (size_t)NBLK * NN;  // 32 KB
    unsigned* arrive = (unsigned*)(colacc + NN);  // 1 KB

    static bool attr_done = false;
    if (!attr_done) {
        (void)hipFuncSetAttribute((const void*)k_sink,
                                  hipFuncAttributeMaxDynamicSharedMemorySize,
                                  SMEM_BYTES);
        attr_done = true;
    }

    k_binit<<<1, NBLK, 0, stream>>>(arrive);

    void* args[] = {(void*)&W, (void*)&P, (void*)&H,
                    (void*)&part, (void*)&colacc, (void*)&arrive};
    (void)hipLaunchCooperativeKernel((const void*)k_sink, dim3(NBLK), dim3(TPB),
                                     args, SMEM_BYTES, stream);
}